// Round 1
// 791.441 us; speedup vs baseline: 1.5266x; 1.5266x over previous
//
#include <hip/hip_runtime.h>

#define N_PIX 16384   // 128*128
#define CC    192
#define C3    576
#define KK    192     // GEMM K (=CC)
#define HD    24

typedef __attribute__((ext_vector_type(8))) short short8;   // 8 bf16 = 4 VGPR
typedef __attribute__((ext_vector_type(4))) float f32x4;    // MFMA acc

__device__ __forceinline__ unsigned short f2bf(float x) {
    unsigned u = __float_as_uint(x);
    u += 0x7fff + ((u >> 16) & 1);          // round-to-nearest-even
    return (unsigned short)(u >> 16);
}
__device__ __forceinline__ float bf2f(unsigned short s) {
    return __uint_as_float(((unsigned)s) << 16);
}
__device__ __forceinline__ int pack2(unsigned short lo, unsigned short hi) {
    return (int)(((unsigned)hi << 16) | (unsigned)lo);
}

// K0: fp32 -> bf16 bulk convert (vector of 4)
__global__ __launch_bounds__(256) void cvt_f32_bf16(const float* __restrict__ src,
                                                    unsigned short* __restrict__ dst, int n4) {
    int i = blockIdx.x * 256 + threadIdx.x;
    if (i < n4) {
        float4 v = ((const float4*)src)[i];
        ushort4 o;
        o.x = f2bf(v.x); o.y = f2bf(v.y); o.z = f2bf(v.z); o.w = f2bf(v.w);
        ((ushort4*)dst)[i] = o;
    }
}

// ---------------------------------------------------------------------------
// bf16 MFMA GEMM body: C[m0+192, n0+128] = A[*,192] @ B[192, N_PIX]
// 256 threads = 4 waves (2x2), wave tile 96x64, 16x16x32 bf16 MFMA.
// A: bf16 row-major [M][192]. B: fp32 or bf16 [192][N_PIX]. C: bf16 or fp32.
// ---------------------------------------------------------------------------
template<bool B_F32, bool C_BF16>
__device__ __forceinline__ void mfma_gemm(const unsigned short* __restrict__ Abf,
                                          const void* __restrict__ Bsrc,
                                          void* __restrict__ Cdst,
                                          int m0, int n0) {
    __shared__ unsigned short As[192][40];   // [m][k], +8 pad (80B stride, 2-way = free)
    __shared__ unsigned short Bs[128][40];   // [n][k]

    const int tid  = threadIdx.x;
    const int wave = tid >> 6, lane = tid & 63;
    const int quad = lane >> 4, l15 = lane & 15;
    const int wr = wave >> 1, wc = wave & 1;

    f32x4 acc[6][4];
#pragma unroll
    for (int i = 0; i < 6; i++)
#pragma unroll
        for (int j = 0; j < 4; j++) acc[i][j] = (f32x4)0.f;

    const int kq = tid & 3;        // B staging: k-chunk (kq*8)
    const int nq = tid >> 2;       // B staging: n-pair (nq*2)

    for (int k0 = 0; k0 < KK; k0 += 32) {
        // ---- stage A: 192x32 bf16, 3 x 16B per thread ----
#pragma unroll
        for (int c = 0; c < 3; c++) {
            int ch  = tid + c * 256;
            int row = ch >> 2, kc = (ch & 3) * 8;
            *(int4*)&As[row][kc] = *(const int4*)(Abf + (long)(m0 + row) * KK + k0 + kc);
        }
        // ---- stage B: 32x128, transpose to [n][k], cvt if fp32 ----
        if (B_F32) {
            const float* Bp = (const float*)Bsrc;
            float2 v[8];
#pragma unroll
            for (int j = 0; j < 8; j++)
                v[j] = *(const float2*)(Bp + (long)(k0 + kq * 8 + j) * N_PIX + n0 + nq * 2);
#pragma unroll
            for (int i = 0; i < 2; i++) {
                unsigned short us[8];
#pragma unroll
                for (int j = 0; j < 8; j++) us[j] = f2bf(i ? v[j].y : v[j].x);
                int4 pk = make_int4(pack2(us[0], us[1]), pack2(us[2], us[3]),
                                    pack2(us[4], us[5]), pack2(us[6], us[7]));
                *(int4*)&Bs[nq * 2 + i][kq * 8] = pk;
            }
        } else {
            const unsigned short* Bp = (const unsigned short*)Bsrc;
            ushort2 v[8];
#pragma unroll
            for (int j = 0; j < 8; j++)
                v[j] = *(const ushort2*)(Bp + (long)(k0 + kq * 8 + j) * N_PIX + n0 + nq * 2);
#pragma unroll
            for (int i = 0; i < 2; i++) {
                unsigned short us[8];
#pragma unroll
                for (int j = 0; j < 8; j++) us[j] = i ? v[j].y : v[j].x;
                int4 pk = make_int4(pack2(us[0], us[1]), pack2(us[2], us[3]),
                                    pack2(us[4], us[5]), pack2(us[6], us[7]));
                *(int4*)&Bs[nq * 2 + i][kq * 8] = pk;
            }
        }
        __syncthreads();

        short8 a[6], b[4];
#pragma unroll
        for (int mi = 0; mi < 6; mi++)
            a[mi] = *(const short8*)&As[wr * 96 + mi * 16 + l15][quad * 8];
#pragma unroll
        for (int ni = 0; ni < 4; ni++)
            b[ni] = *(const short8*)&Bs[wc * 64 + ni * 16 + l15][quad * 8];
#pragma unroll
        for (int mi = 0; mi < 6; mi++)
#pragma unroll
            for (int ni = 0; ni < 4; ni++)
                acc[mi][ni] = __builtin_amdgcn_mfma_f32_16x16x32_bf16(a[mi], b[ni], acc[mi][ni], 0, 0, 0);
        __syncthreads();
    }

    // ---- epilogue: C/D layout col=lane&15, row=quad*4+reg ----
#pragma unroll
    for (int mi = 0; mi < 6; mi++)
#pragma unroll
        for (int ni = 0; ni < 4; ni++)
#pragma unroll
            for (int r = 0; r < 4; r++) {
                int row = m0 + wr * 96 + mi * 16 + quad * 4 + r;
                int col = n0 + wc * 64 + ni * 16 + l15;
                if (C_BF16)
                    ((unsigned short*)Cdst)[(long)row * N_PIX + col] = f2bf(acc[mi][ni][r]);
                else
                    ((float*)Cdst)[(long)row * N_PIX + col] = acc[mi][ni][r];
            }
}

// K1: Y[z][576,N] = w_bf[576,192] @ x[z][192,N]   (z = mod*8+b), bf16 out
__global__ __launch_bounds__(256, 2) void qkv_mfma(const unsigned short* __restrict__ wbf,
                                                   const float* __restrict__ rgb,
                                                   const float* __restrict__ ir,
                                                   unsigned short* __restrict__ Ybf) {
    const int z = blockIdx.z, mod = z >> 3, b = z & 7;
    const float* x = (mod ? ir : rgb) + (long)b * CC * N_PIX;
    unsigned short* y = Ybf + (long)z * C3 * N_PIX;
    mfma_gemm<true, true>(wbf, x, y, blockIdx.y * 192, blockIdx.x * 128);
}

// K5: out[z][192,N] = weff_bf[z][192,192] @ V[z][192,N], fp32 out
__global__ __launch_bounds__(256, 2) void out_mfma(const unsigned short* __restrict__ weff,
                                                   const unsigned short* __restrict__ Zbf,
                                                   float* __restrict__ out) {
    const int z = blockIdx.z;   // o*8+b; V modality == o
    const unsigned short* V = Zbf + ((long)z * C3 + 2 * CC) * N_PIX;
    float* C = out + (long)z * CC * N_PIX;
    mfma_gemm<false, false>(weff + (long)z * CC * CC, V, C, 0, blockIdx.x * 128);
}

// K2 v2: depthwise 3x3 SAME, bf16 in/out, 8 px/thread, vector loads + lane shuffles.
// 16 threads cover one 128-px row; row boundaries align with (lane&15) boundaries,
// so halo columns come from shfl_up/down and edge zeroing is a 2-op predicate.
__global__ __launch_bounds__(256) void dwconv3x3(const unsigned short* __restrict__ Ybf,
                                                 const float* __restrict__ wdw,
                                                 unsigned short* __restrict__ Zbf) {
    const int z  = blockIdx.z;
    const int oc = blockIdx.y;
    const int idx = blockIdx.x * 256 + threadIdx.x;   // 0..2047
    const int p0  = idx * 8;
    const int h   = p0 >> 7;
    const int w0  = p0 & 127;
    const int wq  = threadIdx.x & 15;                 // == w0/8
    const unsigned short* Yc = Ybf + ((long)z * C3 + oc) * N_PIX;

    float wk[9];
#pragma unroll
    for (int i = 0; i < 9; i++) wk[i] = wdw[oc * 9 + i];

    // load all 3 rows up front (independent 16B loads -> MLP)
    float f[3][8];
#pragma unroll
    for (int ry = 0; ry < 3; ry++) {
        const int hy = h + ry - 1;
        int4 raw = make_int4(0, 0, 0, 0);
        if (hy >= 0 && hy <= 127)
            raw = *(const int4*)(Yc + hy * 128 + w0);
        f[ry][0] = bf2f((unsigned short)(raw.x & 0xffff));
        f[ry][1] = bf2f((unsigned short)((unsigned)raw.x >> 16));
        f[ry][2] = bf2f((unsigned short)(raw.y & 0xffff));
        f[ry][3] = bf2f((unsigned short)((unsigned)raw.y >> 16));
        f[ry][4] = bf2f((unsigned short)(raw.z & 0xffff));
        f[ry][5] = bf2f((unsigned short)((unsigned)raw.z >> 16));
        f[ry][6] = bf2f((unsigned short)(raw.w & 0xffff));
        f[ry][7] = bf2f((unsigned short)((unsigned)raw.w >> 16));
    }

    float acc[8];
#pragma unroll
    for (int j = 0; j < 8; j++) acc[j] = 0.f;

#pragma unroll
    for (int ry = 0; ry < 3; ry++) {
        // halo columns: neighbor lanes hold the same rows (same wq group)
        float l = __shfl_up(f[ry][7], 1);
        float r = __shfl_down(f[ry][0], 1);
        if (wq == 0)  l = 0.f;   // w == -1 -> zero pad
        if (wq == 15) r = 0.f;   // w == 128 -> zero pad
        const float wl = wk[ry * 3 + 0], wc = wk[ry * 3 + 1], wr = wk[ry * 3 + 2];
        acc[0] = fmaf(wl, l, acc[0]);
#pragma unroll
        for (int j = 1; j < 8; j++) acc[j] = fmaf(wl, f[ry][j - 1], acc[j]);
#pragma unroll
        for (int j = 0; j < 8; j++) acc[j] = fmaf(wc, f[ry][j], acc[j]);
#pragma unroll
        for (int j = 0; j < 7; j++) acc[j] = fmaf(wr, f[ry][j + 1], acc[j]);
        acc[7] = fmaf(wr, r, acc[7]);
    }

    ushort4 o[2];
    unsigned short* po = (unsigned short*)o;
#pragma unroll
    for (int j = 0; j < 8; j++) po[j] = f2bf(acc[j]);
    *(int4*)(Zbf + ((long)z * C3 + oc) * N_PIX + p0) = *(const int4*)o;
}

// K3a: partial Gram G[24,24] + row sum-of-squares, bf16 input, fp32 math
__global__ __launch_bounds__(64) void gram_partial(const unsigned short* __restrict__ Zbf,
                                                   float* __restrict__ gpart) {
    const int split = blockIdx.x;
    const int bh    = blockIdx.y;
    const int which = blockIdx.z;
    const int b = bh >> 3, head = bh & 7;
    const int zq = (which == 0) ? b : 8 + b;
    const int zk = (which == 0) ? 8 + b : b;
    const unsigned short* Q  = Zbf + ((long)zq * C3 + head * HD) * N_PIX;
    const unsigned short* Kr = Zbf + ((long)zk * C3 + CC + head * HD) * N_PIX;

    __shared__ float Qc[24][132];
    __shared__ float Kc[24][132];

    const int t = threadIdx.x;
    const int ci = t >> 3, di = t & 7;
    const int c0 = ci * 3, d0 = di * 3;

    float acc[3][3];
#pragma unroll
    for (int i = 0; i < 3; i++)
#pragma unroll
        for (int j = 0; j < 3; j++) acc[i][j] = 0.f;
    float ss = 0.f;

    const int n0base = split * 2048;
    for (int nc = 0; nc < 2048; nc += 128) {
        const long n0 = n0base + nc;
        const unsigned short* src = nullptr;
        float* dstrow = nullptr;
        if (t < 24)               { src = Q  + (long)t * N_PIX + n0;        dstrow = Qc[t]; }
        else if (t >= 32 && t < 56) { src = Kr + (long)(t - 32) * N_PIX + n0; dstrow = Kc[t - 32]; }
        if (src) {
#pragma unroll 4
            for (int i = 0; i < 16; i++) {
                int4 raw = *(const int4*)(src + i * 8);
                float f[8];
                f[0] = bf2f((unsigned short)(raw.x & 0xffff)); f[1] = bf2f((unsigned short)((unsigned)raw.x >> 16));
                f[2] = bf2f((unsigned short)(raw.y & 0xffff)); f[3] = bf2f((unsigned short)((unsigned)raw.y >> 16));
                f[4] = bf2f((unsigned short)(raw.z & 0xffff)); f[5] = bf2f((unsigned short)((unsigned)raw.z >> 16));
                f[6] = bf2f((unsigned short)(raw.w & 0xffff)); f[7] = bf2f((unsigned short)((unsigned)raw.w >> 16));
                *(float4*)&dstrow[i * 8]     = make_float4(f[0], f[1], f[2], f[3]);
                *(float4*)&dstrow[i * 8 + 4] = make_float4(f[4], f[5], f[6], f[7]);
#pragma unroll
                for (int q = 0; q < 8; q++) ss = fmaf(f[q], f[q], ss);
            }
        }
        __syncthreads();
#pragma unroll 4
        for (int kk = 0; kk < 128; kk += 4) {
            float4 qv[3], kv[3];
#pragma unroll
            for (int i = 0; i < 3; i++) qv[i] = *(const float4*)&Qc[c0 + i][kk];
#pragma unroll
            for (int j = 0; j < 3; j++) kv[j] = *(const float4*)&Kc[d0 + j][kk];
#pragma unroll
            for (int i = 0; i < 3; i++)
#pragma unroll
                for (int j = 0; j < 3; j++)
                    acc[i][j] += qv[i].x * kv[j].x + qv[i].y * kv[j].y +
                                 qv[i].z * kv[j].z + qv[i].w * kv[j].w;
        }
        __syncthreads();
    }

    const int g = (which * 64 + bh) * 8 + split;
    float* gp = gpart + (long)g * 624;
#pragma unroll
    for (int i = 0; i < 3; i++)
#pragma unroll
        for (int j = 0; j < 3; j++)
            gp[(c0 + i) * 24 + (d0 + j)] = acc[i][j];
    if (t < 24) gp[576 + t] = ss;
    else if (t >= 32 && t < 56) gp[600 + (t - 32)] = ss;
}

// K3b: reduce splits, normalize, temperature, softmax -> P fp32
__global__ __launch_bounds__(256) void gram_reduce_softmax(const float* __restrict__ gpart,
                                                           const float* __restrict__ temperature,
                                                           float* __restrict__ P) {
    const int g = blockIdx.x;           // which*64 + b*8 + head
    const int head = g & 7;
    __shared__ float Gs[576];
    __shared__ float qs[24], ks[24], invq[24], invk[24];

    const int t = threadIdx.x;
    for (int e = t; e < 624; e += 256) {
        float s = 0.f;
        for (int sp = 0; sp < 8; sp++) s += gpart[(long)(g * 8 + sp) * 624 + e];
        if (e < 576) Gs[e] = s;
        else if (e < 600) qs[e - 576] = s;
        else ks[e - 600] = s;
    }
    __syncthreads();
    if (t < 24) {
        invq[t] = 1.f / fmaxf(sqrtf(qs[t]), 1e-12f);
        invk[t] = 1.f / fmaxf(sqrtf(ks[t]), 1e-12f);
    }
    __syncthreads();
    if (t < 24) {
        const float temp = temperature[head];
        float row[24];
        float m = -1e30f;
#pragma unroll
        for (int d = 0; d < 24; d++) {
            row[d] = Gs[t * 24 + d] * invq[t] * invk[d] * temp;
            m = fmaxf(m, row[d]);
        }
        float ssum = 0.f;
#pragma unroll
        for (int d = 0; d < 24; d++) {
            row[d] = expf(row[d] - m);
            ssum += row[d];
        }
        const float inv = 1.f / ssum;
#pragma unroll
        for (int d = 0; d < 24; d++)
            P[(long)g * 576 + t * 24 + d] = row[d] * inv;
    }
}

// K4: weff_bf[o][b] = wproj @ blockdiag(P[1-o][b])  (bf16 out)
__global__ __launch_bounds__(256) void build_weff(const float* __restrict__ wproj,
                                                  const float* __restrict__ P,
                                                  unsigned short* __restrict__ weff) {
    const int o = blockIdx.z, b = blockIdx.y;
    const int e = blockIdx.x * 256 + threadIdx.x;   // 0..36863
    const int co = e / 192, col = e % 192;
    const int head = col / 24, d = col % 24;
    const int which = 1 - o;
    const float* Pp = P + (long)(which * 64 + b * 8 + head) * 576;
    const float* wp = wproj + co * 192 + head * 24;
    float acc = 0.f;
#pragma unroll
    for (int hc = 0; hc < 24; hc++)
        acc = fmaf(wp[hc], Pp[hc * 24 + d], acc);
    weff[((long)(o * 8 + b) * 192 + co) * 192 + col] = f2bf(acc);
}

extern "C" void kernel_launch(void* const* d_in, const int* in_sizes, int n_in,
                              void* d_out, int out_size, void* d_ws, size_t ws_size,
                              hipStream_t stream) {
    (void)in_sizes; (void)n_in; (void)out_size; (void)ws_size;
    const float* rgb    = (const float*)d_in[0];
    const float* ir     = (const float*)d_in[1];
    const float* w_qkv  = (const float*)d_in[2];
    const float* w_dw   = (const float*)d_in[3];
    const float* w_proj = (const float*)d_in[4];
    const float* temp   = (const float*)d_in[5];
    float* out = (float*)d_out;

    char* wsb = (char*)d_ws;
    unsigned short* Y_bf    = (unsigned short*)(wsb);                 // 301,989,888 B
    unsigned short* Z_bf    = (unsigned short*)(wsb + 301989888L);    // 301,989,888 B
    unsigned short* w_bf    = (unsigned short*)(wsb + 603979776L);    //     221,184 B
    unsigned short* weff_bf = (unsigned short*)(wsb + 604200960L);    //   1,179,648 B
    float*          gpart   = (float*)(wsb + 605380608L);             //   2,555,904 B
    float*          P       = (float*)(wsb + 607936512L);             //     294,912 B

    cvt_f32_bf16<<<108, 256, 0, stream>>>(w_qkv, w_bf, 27648);
    qkv_mfma<<<dim3(128, 3, 16), 256, 0, stream>>>(w_bf, rgb, ir, Y_bf);
    dwconv3x3<<<dim3(8, 576, 16), 256, 0, stream>>>(Y_bf, w_dw, Z_bf);
    gram_partial<<<dim3(8, 64, 2), 64, 0, stream>>>(Z_bf, gpart);
    gram_reduce_softmax<<<128, 256, 0, stream>>>(gpart, temp, P);
    build_weff<<<dim3(144, 8, 2), 256, 0, stream>>>(w_proj, P, weff_bf);
    out_mfma<<<dim3(128, 1, 16), 256, 0, stream>>>(weff_bf, Z_bf, out);
}